// Round 1
// baseline (111.481 us; speedup 1.0000x reference)
//
#include <hip/hip_runtime.h>

// MicrotubuleAttention — exact algebraic reduction.
//
// The GTP term (1 - exp(-gamma*dist)) * (-1e9) with gamma >= 1e-4 (clip) makes
// every off-diagonal softmax argument <= -99000 => expf underflows to exactly
// 0.0f. Softmax is exactly one-hot on k == q, so attention output == V_rep and
//   final = x @ Wv @ Weff,   Weff[c,m] = sum_{r=0..3} Wo[(4*(c/64)+r)*64 + c%64, m]
// (GQA head replication folded into Wo). RoPE/Q/K/polarity are dead code.

static constexpr int DMODEL = 1024;
static constexpr int KVDIM  = 256;   // H_KV * D_HEAD
static constexpr int ROWS   = 4096;  // B * T

// Weff[c][m] = sum over the 4 query heads that share kv-head (c>>6)
__global__ void fold_wo_kernel(const float* __restrict__ Wo, float* __restrict__ Weff) {
    int idx = blockIdx.x * blockDim.x + threadIdx.x;   // 256*1024 total
    int m = idx & (DMODEL - 1);
    int c = idx >> 10;
    int kh = c >> 6;
    int d  = c & 63;
    const float* base = Wo + (size_t)((4 * kh) * 64 + d) * DMODEL + m;
    Weff[idx] = base[0]
              + base[(size_t)64  * DMODEL]
              + base[(size_t)128 * DMODEL]
              + base[(size_t)192 * DMODEL];
}

// Plain f32 tiled GEMM: C[M,N] = A[M,K] @ B[K,N], all row-major.
// BM=BN=64, BK=16, 256 threads, 4x4 register tile per thread.
// Requires M%64==0, N%64==0, K%16==0 (holds: 4096/1024/256).
template<int BM, int BN, int BK>
__launch_bounds__(256)
__global__ void gemm_f32_kernel(const float* __restrict__ A, const float* __restrict__ B,
                                float* __restrict__ C, int M, int N, int K) {
    constexpr int ASTRIDE = BK + 4;   // 20 words; 80B rows keep float4 alignment
    constexpr int BSTRIDE = BN + 4;   // 68 words; 272B rows keep float4 alignment
    __shared__ float As[BM * ASTRIDE];
    __shared__ float Bs[BK * BSTRIDE];

    const int tid  = threadIdx.x;
    const int tx   = tid & 15;        // output col group
    const int ty   = tid >> 4;        // output row group
    const int brow = blockIdx.y * BM;
    const int bcol = blockIdx.x * BN;

    // A staging: 64 rows x 16 cols = 256 float4, one per thread
    const int arow = tid >> 2;
    const int af4  = tid & 3;
    // B staging: 16 rows x 64 cols = 256 float4, one per thread
    const int brw  = tid >> 4;
    const int bf4  = tid & 15;

    float acc[4][4] = {};

    for (int kt = 0; kt < K; kt += BK) {
        float4 av = *reinterpret_cast<const float4*>(
            A + (size_t)(brow + arow) * K + kt + af4 * 4);
        float4 bv = *reinterpret_cast<const float4*>(
            B + (size_t)(kt + brw) * N + bcol + bf4 * 4);

        __syncthreads();  // previous iteration's LDS reads complete
        *reinterpret_cast<float4*>(&As[arow * ASTRIDE + af4 * 4]) = av;
        *reinterpret_cast<float4*>(&Bs[brw  * BSTRIDE + bf4 * 4]) = bv;
        __syncthreads();

        #pragma unroll
        for (int k = 0; k < BK; ++k) {
            float a0 = As[(ty * 4 + 0) * ASTRIDE + k];
            float a1 = As[(ty * 4 + 1) * ASTRIDE + k];
            float a2 = As[(ty * 4 + 2) * ASTRIDE + k];
            float a3 = As[(ty * 4 + 3) * ASTRIDE + k];
            float4 bvv = *reinterpret_cast<const float4*>(&Bs[k * BSTRIDE + tx * 4]);
            acc[0][0] += a0 * bvv.x; acc[0][1] += a0 * bvv.y;
            acc[0][2] += a0 * bvv.z; acc[0][3] += a0 * bvv.w;
            acc[1][0] += a1 * bvv.x; acc[1][1] += a1 * bvv.y;
            acc[1][2] += a1 * bvv.z; acc[1][3] += a1 * bvv.w;
            acc[2][0] += a2 * bvv.x; acc[2][1] += a2 * bvv.y;
            acc[2][2] += a2 * bvv.z; acc[2][3] += a2 * bvv.w;
            acc[3][0] += a3 * bvv.x; acc[3][1] += a3 * bvv.y;
            acc[3][2] += a3 * bvv.z; acc[3][3] += a3 * bvv.w;
        }
    }

    #pragma unroll
    for (int i = 0; i < 4; ++i) {
        float4 v;
        v.x = acc[i][0]; v.y = acc[i][1]; v.z = acc[i][2]; v.w = acc[i][3];
        *reinterpret_cast<float4*>(
            C + (size_t)(brow + ty * 4 + i) * N + bcol + tx * 4) = v;
    }
}

extern "C" void kernel_launch(void* const* d_in, const int* in_sizes, int n_in,
                              void* d_out, int out_size, void* d_ws, size_t ws_size,
                              hipStream_t stream) {
    const float* x  = (const float*)d_in[0];   // (B*T, 1024)
    const float* Wv = (const float*)d_in[3];   // (1024, 256)
    const float* Wo = (const float*)d_in[4];   // (1024, 1024)
    float* out = (float*)d_out;                // (B*T, 1024)

    float* Weff  = (float*)d_ws;               // 256*1024 f32 = 1 MB
    float* Vflat = Weff + KVDIM * DMODEL;      // 4096*256 f32 = 4 MB

    // Weff = head-replication-folded Wo
    fold_wo_kernel<<<(KVDIM * DMODEL) / 256, 256, 0, stream>>>(Wo, Weff);

    // Vflat = x @ Wv          (4096 x 256, K = 1024)
    gemm_f32_kernel<64, 64, 16><<<dim3(KVDIM / 64, ROWS / 64), 256, 0, stream>>>(
        x, Wv, Vflat, ROWS, KVDIM, DMODEL);

    // out = Vflat @ Weff      (4096 x 1024, K = 256)
    gemm_f32_kernel<64, 64, 16><<<dim3(DMODEL / 64, ROWS / 64), 256, 0, stream>>>(
        Vflat, Weff, out, ROWS, DMODEL, KVDIM);
}

// Round 2
// 49.577 us; speedup vs baseline: 2.2486x; 2.2486x over previous
//
#include <hip/hip_runtime.h>
#include <hip/hip_bf16.h>

// MicrotubuleAttention — exact algebraic reduction + bf16 MFMA.
//
// GTP penalty: (1 - exp(-gamma*dist))*(-1e9), gamma >= 1e-4 => every
// off-diagonal softmax argument <= -9.9e4 => expf underflows to exactly 0.
// Softmax is exactly one-hot at k==q, so attention output == V_rep and
//   out = x @ Wv @ Weff = x @ Wcomb
// with Weff[c][m] = sum_{r=0..3} Wo[(4*(c>>6)+r)*64 + (c&63)][m]  (GQA fold).
// RoPE/Q/K/polarity are dead code.  Pipeline:
//   1. xb     = bf16(x)                        [4096,1024]
//   2. Wvb    = bf16(Wv)                       [1024,256]   (= B^T for GEMM A)
//   3. WeffT  = bf16(fold(Wo))                 [1024,256]   (WeffT[m][c])
//   4. WcombT = WeffT @ Wvb^T   (MFMA, bf16)   [1024,1024]  (WcombT[m][d])
//   5. out    = xb @ WcombT^T   (MFMA, f32)    [4096,1024]

using bf16x8 = __attribute__((ext_vector_type(8))) short;
using f32x4  = __attribute__((ext_vector_type(4))) float;

static constexpr int DMODEL = 1024;
static constexpr int KVDIM  = 256;   // H_KV * D_HEAD
static constexpr int ROWS   = 4096;  // B * T

__device__ inline unsigned short f2bf(float f) {
    __hip_bfloat16 h = __float2bfloat16(f);   // RNE
    return *reinterpret_cast<unsigned short*>(&h);
}

// float4-vectorized f32 -> bf16 convert (n4 = elements/4)
__global__ void cvt_kernel(const float* __restrict__ in,
                           unsigned short* __restrict__ out, int n4) {
    int i = blockIdx.x * blockDim.x + threadIdx.x;
    if (i >= n4) return;
    float4 v = reinterpret_cast<const float4*>(in)[i];
    ushort4 o;
    o.x = f2bf(v.x); o.y = f2bf(v.y); o.z = f2bf(v.z); o.w = f2bf(v.w);
    reinterpret_cast<ushort4*>(out)[i] = o;
}

// WeffT[m][c] = sum_{r=0..3} Wo[(4*(c>>6)+r)*64 + (c&63)][m], bf16 out
__global__ void fold_kernel(const float* __restrict__ Wo,
                            unsigned short* __restrict__ WeffT) {
    int idx = blockIdx.x * blockDim.x + threadIdx.x;  // 1024*256
    int c = idx & (KVDIM - 1);
    int m = idx >> 8;
    const float* base = Wo + (size_t)((c >> 6) * 4 * 64 + (c & 63)) * DMODEL + m;
    float s = base[0]
            + base[(size_t) 64 * DMODEL]
            + base[(size_t)128 * DMODEL]
            + base[(size_t)192 * DMODEL];
    WeffT[(size_t)m * KVDIM + c] = f2bf(s);
}

// bf16 MFMA GEMM: C[M][N] = A[M][K] @ Bt[N][K]^T (both row-major bf16).
// BM=128, BN=64, BK=64; 256 threads = 4 waves, each wave owns a 64x32
// output sub-tile as 4x2 fragments of 16x16 (mfma_f32_16x16x32_bf16).
// Staging via global_load_lds width=16, linear LDS (m97 structure).
// Requires M%128==0, N%64==0, K%64==0.
template<bool OUT_BF16>
__launch_bounds__(256, 2)
__global__ void gemm_bf16_mfma(const unsigned short* __restrict__ A,
                               const unsigned short* __restrict__ Bt,
                               void* __restrict__ Cout,
                               int M, int N, int K) {
    __shared__ short As[128 * 64];   // [row][k] linear, 16 KB
    __shared__ short Bs[64 * 64];    // [col][k] linear,  8 KB

    const int tid  = threadIdx.x;
    const int lane = tid & 63;
    const int w    = tid >> 6;       // wave 0..3
    const int wr   = w >> 1;         // wave row (0..1) -> 64 rows each
    const int wc   = w & 1;          // wave col (0..1) -> 32 cols each
    const int brow = blockIdx.y * 128;
    const int bcol = blockIdx.x * 64;

    const int lrow8 = lane >> 3;        // row within an 8-row staging chunk
    const int lkoff = (lane & 7) * 8;   // k-element offset (16B per lane)
    const int lr    = lane & 15;        // fragment row/col
    const int kg    = (lane >> 4) * 8;  // fragment k-group base

    f32x4 acc[4][2] = {};

    for (int kt = 0; kt < K; kt += 64) {
        if (kt) __syncthreads();  // all waves done reading LDS from prev iter
        // stage A tile [128][64]: 16 chunks of 8 rows; wave w -> chunks w*4+i
        #pragma unroll
        for (int i = 0; i < 4; ++i) {
            const int ch = w * 4 + i;
            const unsigned short* g =
                A + (size_t)(brow + ch * 8 + lrow8) * K + kt + lkoff;
            __builtin_amdgcn_global_load_lds(
                (const __attribute__((address_space(1))) void*)g,
                (__attribute__((address_space(3))) void*)(As + ch * 512),
                16, 0, 0);
        }
        // stage B tile [64][64]: 8 chunks; wave w -> chunks w*2+i
        #pragma unroll
        for (int i = 0; i < 2; ++i) {
            const int ch = w * 2 + i;
            const unsigned short* g =
                Bt + (size_t)(bcol + ch * 8 + lrow8) * K + kt + lkoff;
            __builtin_amdgcn_global_load_lds(
                (const __attribute__((address_space(1))) void*)g,
                (__attribute__((address_space(3))) void*)(Bs + ch * 512),
                16, 0, 0);
        }
        __syncthreads();  // compiler drains vmcnt(0) before the barrier

        #pragma unroll
        for (int ks = 0; ks < 2; ++ks) {
            bf16x8 a[4], b[2];
            #pragma unroll
            for (int m = 0; m < 4; ++m)
                a[m] = *reinterpret_cast<const bf16x8*>(
                    &As[(wr * 64 + m * 16 + lr) * 64 + ks * 32 + kg]);
            #pragma unroll
            for (int n = 0; n < 2; ++n)
                b[n] = *reinterpret_cast<const bf16x8*>(
                    &Bs[(wc * 32 + n * 16 + lr) * 64 + ks * 32 + kg]);
            #pragma unroll
            for (int m = 0; m < 4; ++m)
                #pragma unroll
                for (int n = 0; n < 2; ++n)
                    acc[m][n] = __builtin_amdgcn_mfma_f32_16x16x32_bf16(
                        a[m], b[n], acc[m][n], 0, 0, 0);
        }
    }

    // C/D layout: col = lane&15, row = (lane>>4)*4 + reg  (guide m89/m91)
    const int rg = (lane >> 4) * 4;
    #pragma unroll
    for (int m = 0; m < 4; ++m) {
        #pragma unroll
        for (int n = 0; n < 2; ++n) {
            #pragma unroll
            for (int j = 0; j < 4; ++j) {
                const size_t row = brow + wr * 64 + m * 16 + rg + j;
                const size_t col = bcol + wc * 32 + n * 16 + lr;
                if (OUT_BF16)
                    ((unsigned short*)Cout)[row * N + col] = f2bf(acc[m][n][j]);
                else
                    ((float*)Cout)[row * N + col] = acc[m][n][j];
            }
        }
    }
}

extern "C" void kernel_launch(void* const* d_in, const int* in_sizes, int n_in,
                              void* d_out, int out_size, void* d_ws, size_t ws_size,
                              hipStream_t stream) {
    const float* x  = (const float*)d_in[0];   // (4096, 1024)
    const float* Wv = (const float*)d_in[3];   // (1024, 256)
    const float* Wo = (const float*)d_in[4];   // (1024, 1024)
    float* out = (float*)d_out;                // (4096, 1024) f32

    unsigned short* xb     = (unsigned short*)d_ws;          // 8 MB
    unsigned short* WeffT  = xb    + (size_t)ROWS * DMODEL;  // 0.5 MB [m][c]
    unsigned short* Wvb    = WeffT + (size_t)DMODEL * KVDIM; // 0.5 MB [d][c]
    unsigned short* WcombT = Wvb   + (size_t)DMODEL * KVDIM; // 2 MB   [m][d]

    // independent prep
    cvt_kernel<<<(ROWS * DMODEL / 4 + 255) / 256, 256, 0, stream>>>(
        x, xb, ROWS * DMODEL / 4);
    cvt_kernel<<<(DMODEL * KVDIM / 4 + 255) / 256, 256, 0, stream>>>(
        Wv, Wvb, DMODEL * KVDIM / 4);
    fold_kernel<<<(DMODEL * KVDIM) / 256, 256, 0, stream>>>(Wo, WeffT);

    // WcombT[m][d] = sum_c WeffT[m][c] * Wvb[d][c]   (M=1024,N=1024,K=256)
    gemm_bf16_mfma<true><<<dim3(DMODEL / 64, DMODEL / 128), 256, 0, stream>>>(
        WeffT, Wvb, WcombT, DMODEL, DMODEL, KVDIM);

    // out[r][m] = sum_d xb[r][d] * WcombT[m][d]      (M=4096,N=1024,K=1024)
    gemm_bf16_mfma<false><<<dim3(DMODEL / 64, ROWS / 128), 256, 0, stream>>>(
        xb, WcombT, out, ROWS, DMODEL, DMODEL);
}

// Round 3
// 47.635 us; speedup vs baseline: 2.3403x; 1.0408x over previous
//
#include <hip/hip_runtime.h>
#include <hip/hip_bf16.h>

// MicrotubuleAttention — exact algebraic reduction + bf16 MFMA.
//
// GTP penalty: (1 - exp(-gamma*dist))*(-1e9), gamma >= 1e-4 => every
// off-diagonal softmax argument <= -9.9e4 => expf underflows to exactly 0.
// Softmax is exactly one-hot at k==q, so attention output == V_rep and
//   out = x @ Wv @ Weff = x @ Wcomb
// with Weff[c][m] = sum_{r=0..3} Wo[(4*(c>>6)+r)*64 + (c&63)][m]  (GQA fold).
// RoPE/Q/K/polarity are dead code.  Pipeline (3 launches):
//   1. prep:  xb = bf16(x); Wvb = bf16(Wv); WeffT = bf16(fold(Wo))
//   2. WcombT = WeffT @ Wvb^T   (MFMA)   [1024,1024] (WcombT[m][d])
//   3. out    = xb @ WcombT^T   (MFMA)   [4096,1024] f32
// GEMMs: 128x64 tile, BK=64, double-buffered LDS with prefetch-before-compute
// (T3 minimum 2-phase), XCD-chunked block swizzle (T1).

using bf16x8 = __attribute__((ext_vector_type(8))) short;
using f32x4  = __attribute__((ext_vector_type(4))) float;

static constexpr int DMODEL = 1024;
static constexpr int KVDIM  = 256;   // H_KV * D_HEAD
static constexpr int ROWS   = 4096;  // B * T

__device__ inline unsigned short f2bf(float f) {
    __hip_bfloat16 h = __float2bfloat16(f);   // RNE
    return *reinterpret_cast<unsigned short*>(&h);
}

// ---- fused prep: block-range partitioned -------------------------------
static constexpr int XCVT_BLOCKS  = (ROWS * DMODEL) / 4 / 256;      // 4096
static constexpr int WVCVT_BLOCKS = (DMODEL * KVDIM) / 4 / 256;     // 256
static constexpr int FOLD_BLOCKS  = (DMODEL * KVDIM) / 256;         // 1024

__global__ void prep_kernel(const float* __restrict__ x,
                            const float* __restrict__ Wv,
                            const float* __restrict__ Wo,
                            unsigned short* __restrict__ xb,
                            unsigned short* __restrict__ Wvb,
                            unsigned short* __restrict__ WeffT) {
    const int b = blockIdx.x;
    const int t = threadIdx.x;
    if (b < XCVT_BLOCKS) {
        int i = b * 256 + t;
        float4 v = reinterpret_cast<const float4*>(x)[i];
        ushort4 o;
        o.x = f2bf(v.x); o.y = f2bf(v.y); o.z = f2bf(v.z); o.w = f2bf(v.w);
        reinterpret_cast<ushort4*>(xb)[i] = o;
    } else if (b < XCVT_BLOCKS + WVCVT_BLOCKS) {
        int i = (b - XCVT_BLOCKS) * 256 + t;
        float4 v = reinterpret_cast<const float4*>(Wv)[i];
        ushort4 o;
        o.x = f2bf(v.x); o.y = f2bf(v.y); o.z = f2bf(v.z); o.w = f2bf(v.w);
        reinterpret_cast<ushort4*>(Wvb)[i] = o;
    } else {
        int idx = (b - XCVT_BLOCKS - WVCVT_BLOCKS) * 256 + t;  // 256K outputs
        int c = idx & (KVDIM - 1);
        int m = idx >> 8;
        const float* base =
            Wo + (size_t)((c >> 6) * 4 * 64 + (c & 63)) * DMODEL + m;
        float s = base[0]
                + base[(size_t) 64 * DMODEL]
                + base[(size_t)128 * DMODEL]
                + base[(size_t)192 * DMODEL];
        WeffT[(size_t)m * KVDIM + c] = f2bf(s);
    }
}

// ---- bf16 MFMA GEMM: C[M][N] = A[M][K] @ Bt[N][K]^T ---------------------
// BM=128, BN=64, BK=64; 256 threads = 4 waves, each wave a 64x32 sub-tile
// as 4x2 fragments of 16x16x32. Double-buffered LDS, prefetch-before-
// compute, one __syncthreads per K-step. Requires M%128==0, N%64==0, K%64==0
// and gridDim.x*gridDim.y % 8 == 0 (XCD swizzle bijectivity).
template<bool OUT_BF16>
__launch_bounds__(256, 2)
__global__ void gemm_bf16_mfma(const unsigned short* __restrict__ A,
                               const unsigned short* __restrict__ Bt,
                               void* __restrict__ Cout,
                               int M, int N, int K) {
    __shared__ short As[2][128 * 64];   // 2 x 16 KB
    __shared__ short Bs[2][64 * 64];    // 2 x  8 KB

    // T1: XCD-chunked bijective swizzle (nwg % 8 == 0 by construction)
    const int gx  = gridDim.x;
    const int nwg = gx * gridDim.y;
    const int bid = blockIdx.y * gx + blockIdx.x;
    const int cpx = nwg >> 3;
    const int swz = (bid & 7) * cpx + (bid >> 3);
    const int brow = (swz / gx) * 128;
    const int bcol = (swz % gx) * 64;

    const int tid  = threadIdx.x;
    const int lane = tid & 63;
    const int w    = tid >> 6;       // wave 0..3
    const int wr   = w >> 1;         // wave row (0..1) -> 64 rows
    const int wc   = w & 1;          // wave col (0..1) -> 32 cols

    const int lrow8 = lane >> 3;        // row within an 8-row staging chunk
    const int lkoff = (lane & 7) * 8;   // k-element offset (16B per lane)
    const int lr    = lane & 15;        // fragment row/col
    const int kg    = (lane >> 4) * 8;  // fragment k-group base

    f32x4 acc[4][2] = {};

    auto stage = [&](int buf, int kt) {
        #pragma unroll
        for (int i = 0; i < 4; ++i) {
            const int ch = w * 4 + i;                       // 0..15
            const unsigned short* g =
                A + (size_t)(brow + ch * 8 + lrow8) * K + kt + lkoff;
            __builtin_amdgcn_global_load_lds(
                (const __attribute__((address_space(1))) void*)g,
                (__attribute__((address_space(3))) void*)(&As[buf][ch * 512]),
                16, 0, 0);
        }
        #pragma unroll
        for (int i = 0; i < 2; ++i) {
            const int ch = w * 2 + i;                       // 0..7
            const unsigned short* g =
                Bt + (size_t)(bcol + ch * 8 + lrow8) * K + kt + lkoff;
            __builtin_amdgcn_global_load_lds(
                (const __attribute__((address_space(1))) void*)g,
                (__attribute__((address_space(3))) void*)(&Bs[buf][ch * 512]),
                16, 0, 0);
        }
    };

    stage(0, 0);
    __syncthreads();                 // vmcnt(0) drain + barrier
    const int nt = K >> 6;
    int cur = 0;
    for (int t = 0; t < nt; ++t) {
        if (t + 1 < nt) stage(cur ^ 1, (t + 1) << 6);   // prefetch in flight
        #pragma unroll
        for (int ks = 0; ks < 2; ++ks) {
            bf16x8 a[4], b[2];
            #pragma unroll
            for (int m = 0; m < 4; ++m)
                a[m] = *reinterpret_cast<const bf16x8*>(
                    &As[cur][(wr * 64 + m * 16 + lr) * 64 + ks * 32 + kg]);
            #pragma unroll
            for (int n = 0; n < 2; ++n)
                b[n] = *reinterpret_cast<const bf16x8*>(
                    &Bs[cur][(wc * 32 + n * 16 + lr) * 64 + ks * 32 + kg]);
            #pragma unroll
            for (int m = 0; m < 4; ++m)
                #pragma unroll
                for (int n = 0; n < 2; ++n)
                    acc[m][n] = __builtin_amdgcn_mfma_f32_16x16x32_bf16(
                        a[m], b[n], acc[m][n], 0, 0, 0);
        }
        __syncthreads();             // drains prefetch + guards LDS reuse
        cur ^= 1;
    }

    // C/D layout: col = lane&15, row = (lane>>4)*4 + reg  (guide m89/m91)
    const int rg = (lane >> 4) * 4;
    #pragma unroll
    for (int m = 0; m < 4; ++m) {
        #pragma unroll
        for (int n = 0; n < 2; ++n) {
            #pragma unroll
            for (int j = 0; j < 4; ++j) {
                const size_t row = brow + wr * 64 + m * 16 + rg + j;
                const size_t col = bcol + wc * 32 + n * 16 + lr;
                if (OUT_BF16)
                    ((unsigned short*)Cout)[row * N + col] = f2bf(acc[m][n][j]);
                else
                    ((float*)Cout)[row * N + col] = acc[m][n][j];
            }
        }
    }
}

extern "C" void kernel_launch(void* const* d_in, const int* in_sizes, int n_in,
                              void* d_out, int out_size, void* d_ws, size_t ws_size,
                              hipStream_t stream) {
    const float* x  = (const float*)d_in[0];   // (4096, 1024)
    const float* Wv = (const float*)d_in[3];   // (1024, 256)
    const float* Wo = (const float*)d_in[4];   // (1024, 1024)
    float* out = (float*)d_out;                // (4096, 1024) f32

    unsigned short* xb     = (unsigned short*)d_ws;          // 8 MB
    unsigned short* WeffT  = xb    + (size_t)ROWS * DMODEL;  // 0.5 MB [m][c]
    unsigned short* Wvb    = WeffT + (size_t)DMODEL * KVDIM; // 0.5 MB [d][c]
    unsigned short* WcombT = Wvb   + (size_t)DMODEL * KVDIM; // 2 MB   [m][d]

    prep_kernel<<<XCVT_BLOCKS + WVCVT_BLOCKS + FOLD_BLOCKS, 256, 0, stream>>>(
        x, Wv, Wo, xb, Wvb, WeffT);

    // WcombT[m][d] = sum_c WeffT[m][c] * Wvb[d][c]   (M=1024,N=1024,K=256)
    gemm_bf16_mfma<true><<<dim3(DMODEL / 64, DMODEL / 128), 256, 0, stream>>>(
        WeffT, Wvb, WcombT, DMODEL, DMODEL, KVDIM);

    // out[r][m] = sum_d xb[r][d] * WcombT[m][d]      (M=4096,N=1024,K=1024)
    gemm_bf16_mfma<false><<<dim3(DMODEL / 64, ROWS / 128), 256, 0, stream>>>(
        xb, WcombT, out, ROWS, DMODEL, DMODEL);
}

// Round 4
// 45.935 us; speedup vs baseline: 2.4270x; 1.0370x over previous
//
#include <hip/hip_runtime.h>
#include <hip/hip_bf16.h>

// MicrotubuleAttention — exact algebraic reduction + bf16 MFMA.
//
// GTP penalty: (1 - exp(-gamma*dist))*(-1e9), gamma >= 1e-4 => every
// off-diagonal softmax argument <= -9.9e4 => expf underflows to exactly 0.
// Softmax is exactly one-hot at k==q, so attention output == V_rep and
//   out = x @ Wv @ Weff = x @ Wcomb
// with Weff[c][m] = sum_{r=0..3} Wo[(4*(c>>6)+r)*64 + (c&63)][m]  (GQA fold).
// RoPE/Q/K/polarity are dead code.  Pipeline (3 launches):
//   1. prep:  xb = bf16(x); Wvb = bf16(Wv); WeffT = bf16(fold(Wo))
//   2. WcombT = WeffT @ Wvb^T   (MFMA)   [1024,1024] (WcombT[m][d])
//   3. out    = xb @ WcombT^T   (MFMA)   [4096,1024] f32
// GEMM: 128x64 tile, BK=64, TRIPLE-buffered LDS, depth-2 prefetch with
// counted s_waitcnt vmcnt(6) + raw s_barrier (one barrier per K-step),
// XCD-chunked block swizzle (T1).

using bf16x8 = __attribute__((ext_vector_type(8))) short;
using f32x4  = __attribute__((ext_vector_type(4))) float;

static constexpr int DMODEL = 1024;
static constexpr int KVDIM  = 256;   // H_KV * D_HEAD
static constexpr int ROWS   = 4096;  // B * T

__device__ inline unsigned short f2bf(float f) {
    __hip_bfloat16 h = __float2bfloat16(f);   // RNE
    return *reinterpret_cast<unsigned short*>(&h);
}

// ---- fused prep: block-range partitioned -------------------------------
static constexpr int XCVT_BLOCKS  = (ROWS * DMODEL) / 4 / 256;      // 4096
static constexpr int WVCVT_BLOCKS = (DMODEL * KVDIM) / 4 / 256;     // 256
static constexpr int FOLD_BLOCKS  = (DMODEL * KVDIM) / 256;         // 1024

__global__ void prep_kernel(const float* __restrict__ x,
                            const float* __restrict__ Wv,
                            const float* __restrict__ Wo,
                            unsigned short* __restrict__ xb,
                            unsigned short* __restrict__ Wvb,
                            unsigned short* __restrict__ WeffT) {
    const int b = blockIdx.x;
    const int t = threadIdx.x;
    if (b < XCVT_BLOCKS) {
        int i = b * 256 + t;
        float4 v = reinterpret_cast<const float4*>(x)[i];
        ushort4 o;
        o.x = f2bf(v.x); o.y = f2bf(v.y); o.z = f2bf(v.z); o.w = f2bf(v.w);
        reinterpret_cast<ushort4*>(xb)[i] = o;
    } else if (b < XCVT_BLOCKS + WVCVT_BLOCKS) {
        int i = (b - XCVT_BLOCKS) * 256 + t;
        float4 v = reinterpret_cast<const float4*>(Wv)[i];
        ushort4 o;
        o.x = f2bf(v.x); o.y = f2bf(v.y); o.z = f2bf(v.z); o.w = f2bf(v.w);
        reinterpret_cast<ushort4*>(Wvb)[i] = o;
    } else {
        int idx = (b - XCVT_BLOCKS - WVCVT_BLOCKS) * 256 + t;  // 256K outputs
        int c = idx & (KVDIM - 1);
        int m = idx >> 8;
        const float* base =
            Wo + (size_t)((c >> 6) * 4 * 64 + (c & 63)) * DMODEL + m;
        float s = base[0]
                + base[(size_t) 64 * DMODEL]
                + base[(size_t)128 * DMODEL]
                + base[(size_t)192 * DMODEL];
        WeffT[(size_t)m * KVDIM + c] = f2bf(s);
    }
}

// ---- bf16 MFMA GEMM: C[M][N] = A[M][K] @ Bt[N][K]^T ---------------------
// BM=128, BN=64, BK=64; 256 threads = 4 waves, each wave a 64x32 sub-tile
// as 4x2 fragments of 16x16x32.  Triple-buffered LDS, depth-2 prefetch,
// counted vmcnt (6 loads/wave/stage, never drained to 0 mid-loop), ONE raw
// s_barrier per K-step.  Requires M%128==0, N%64==0, K%128==0 (nt>=2) and
// gridDim.x*gridDim.y % 8 == 0 (XCD swizzle bijectivity).
template<bool OUT_BF16>
__launch_bounds__(256, 2)
__global__ void gemm_bf16_mfma(const unsigned short* __restrict__ A,
                               const unsigned short* __restrict__ Bt,
                               void* __restrict__ Cout,
                               int M, int N, int K) {
    __shared__ short As[3][128 * 64];   // 3 x 16 KB
    __shared__ short Bs[3][64 * 64];    // 3 x  8 KB

    // T1: XCD-chunked bijective swizzle (nwg % 8 == 0 by construction)
    const int gx  = gridDim.x;
    const int nwg = gx * gridDim.y;
    const int bid = blockIdx.y * gx + blockIdx.x;
    const int cpx = nwg >> 3;
    const int swz = (bid & 7) * cpx + (bid >> 3);
    const int brow = (swz / gx) * 128;
    const int bcol = (swz % gx) * 64;

    const int tid  = threadIdx.x;
    const int lane = tid & 63;
    const int w    = tid >> 6;       // wave 0..3
    const int wr   = w >> 1;         // wave row (0..1) -> 64 rows
    const int wc   = w & 1;          // wave col (0..1) -> 32 cols

    const int lrow8 = lane >> 3;        // row within an 8-row staging chunk
    const int lkoff = (lane & 7) * 8;   // k-element offset (16B per lane)
    const int lr    = lane & 15;        // fragment row/col
    const int kg    = (lane >> 4) * 8;  // fragment k-group base

    f32x4 acc[4][2] = {};

    // 6 global_load_lds per wave per stage (4 A-chunks + 2 B-chunks)
    auto stage = [&](int buf, int kt) {
        #pragma unroll
        for (int i = 0; i < 4; ++i) {
            const int ch = w * 4 + i;                       // 0..15
            const unsigned short* g =
                A + (size_t)(brow + ch * 8 + lrow8) * K + kt + lkoff;
            __builtin_amdgcn_global_load_lds(
                (const __attribute__((address_space(1))) void*)g,
                (__attribute__((address_space(3))) void*)(&As[buf][ch * 512]),
                16, 0, 0);
        }
        #pragma unroll
        for (int i = 0; i < 2; ++i) {
            const int ch = w * 2 + i;                       // 0..7
            const unsigned short* g =
                Bt + (size_t)(bcol + ch * 8 + lrow8) * K + kt + lkoff;
            __builtin_amdgcn_global_load_lds(
                (const __attribute__((address_space(1))) void*)g,
                (__attribute__((address_space(3))) void*)(&Bs[buf][ch * 512]),
                16, 0, 0);
        }
    };

    const int nt = K >> 6;              // >= 2 always here
    stage(0, 0);
    stage(1, 64);
    int bc = 0;                         // buffer holding tile t
    for (int t = 0; t < nt; ++t) {
        // tile t's 6 loads landed; keep tile t+1's 6 in flight (never 0)
        if (t + 1 < nt) asm volatile("s_waitcnt vmcnt(6)" ::: "memory");
        else            asm volatile("s_waitcnt vmcnt(0)" ::: "memory");
        __builtin_amdgcn_s_barrier();   // also guards WAR on buffer bs below

        int bs = bc + 2; if (bs >= 3) bs -= 3;   // == (t+2) % 3
        if (t + 2 < nt) stage(bs, (t + 2) << 6); // depth-2 prefetch in flight

        #pragma unroll
        for (int ks = 0; ks < 2; ++ks) {
            bf16x8 a[4], b[2];
            #pragma unroll
            for (int m = 0; m < 4; ++m)
                a[m] = *reinterpret_cast<const bf16x8*>(
                    &As[bc][(wr * 64 + m * 16 + lr) * 64 + ks * 32 + kg]);
            #pragma unroll
            for (int n = 0; n < 2; ++n)
                b[n] = *reinterpret_cast<const bf16x8*>(
                    &Bs[bc][(wc * 32 + n * 16 + lr) * 64 + ks * 32 + kg]);
            #pragma unroll
            for (int m = 0; m < 4; ++m)
                #pragma unroll
                for (int n = 0; n < 2; ++n)
                    acc[m][n] = __builtin_amdgcn_mfma_f32_16x16x32_bf16(
                        a[m], b[n], acc[m][n], 0, 0, 0);
        }
        bc = (bc == 2) ? 0 : bc + 1;
    }

    // C/D layout: col = lane&15, row = (lane>>4)*4 + reg  (guide m89/m91)
    const int rg = (lane >> 4) * 4;
    #pragma unroll
    for (int m = 0; m < 4; ++m) {
        #pragma unroll
        for (int n = 0; n < 2; ++n) {
            #pragma unroll
            for (int j = 0; j < 4; ++j) {
                const size_t row = brow + wr * 64 + m * 16 + rg + j;
                const size_t col = bcol + wc * 32 + n * 16 + lr;
                if (OUT_BF16)
                    ((unsigned short*)Cout)[row * N + col] = f2bf(acc[m][n][j]);
                else
                    ((float*)Cout)[row * N + col] = acc[m][n][j];
            }
        }
    }
}

extern "C" void kernel_launch(void* const* d_in, const int* in_sizes, int n_in,
                              void* d_out, int out_size, void* d_ws, size_t ws_size,
                              hipStream_t stream) {
    const float* x  = (const float*)d_in[0];   // (4096, 1024)
    const float* Wv = (const float*)d_in[3];   // (1024, 256)
    const float* Wo = (const float*)d_in[4];   // (1024, 1024)
    float* out = (float*)d_out;                // (4096, 1024) f32

    unsigned short* xb     = (unsigned short*)d_ws;          // 8 MB
    unsigned short* WeffT  = xb    + (size_t)ROWS * DMODEL;  // 0.5 MB [m][c]
    unsigned short* Wvb    = WeffT + (size_t)DMODEL * KVDIM; // 0.5 MB [d][c]
    unsigned short* WcombT = Wvb   + (size_t)DMODEL * KVDIM; // 2 MB   [m][d]

    prep_kernel<<<XCVT_BLOCKS + WVCVT_BLOCKS + FOLD_BLOCKS, 256, 0, stream>>>(
        x, Wv, Wo, xb, Wvb, WeffT);

    // WcombT[m][d] = sum_c WeffT[m][c] * Wvb[d][c]   (M=1024,N=1024,K=256)
    gemm_bf16_mfma<true><<<dim3(DMODEL / 64, DMODEL / 128), 256, 0, stream>>>(
        WeffT, Wvb, WcombT, DMODEL, DMODEL, KVDIM);

    // out[r][m] = sum_d xb[r][d] * WcombT[m][d]      (M=4096,N=1024,K=1024)
    gemm_bf16_mfma<false><<<dim3(DMODEL / 64, ROWS / 128), 256, 0, stream>>>(
        xb, WcombT, out, ROWS, DMODEL, DMODEL);
}

// Round 5
// 41.067 us; speedup vs baseline: 2.7146x; 1.1185x over previous
//
#include <hip/hip_runtime.h>
#include <hip/hip_bf16.h>

// MicrotubuleAttention — exact algebraic reduction + bf16 MFMA.
//
// GTP penalty: (1 - exp(-gamma*dist))*(-1e9), gamma >= 1e-4 => every
// off-diagonal softmax argument <= -9.9e4 => expf underflows to exactly 0.
// Softmax is exactly one-hot at k==q, so attention output == V_rep and
//   out = (x @ Wv) @ Weff        (4.3 GFLOP total — half of the x@Wcomb form)
// with Weff[c][m] = sum_{r=0..3} Wo[(4*(c>>6)+r)*64 + (c&63)][m]  (GQA fold).
// RoPE/Q/K/polarity are dead code.  Pipeline (3 launches):
//   1. prep:  xb = bf16(x); WvT = bf16(Wv^T); WeffT = bf16(fold(Wo)^T)
//   2. Vb    = xb @ WvT^T    (MFMA, bf16 out)  [4096,256]   K=1024
//   3. out   = Vb @ WeffT^T  (MFMA, f32 out)   [4096,1024]  K=256
// GEMM: triple-buffered LDS, depth-2 prefetch, counted s_waitcnt vmcnt
// (never 0 mid-loop), one s_barrier per K-step, XCD-chunked swizzle (T1).

using bf16x8 = __attribute__((ext_vector_type(8))) short;
using f32x4  = __attribute__((ext_vector_type(4))) float;

static constexpr int DMODEL = 1024;
static constexpr int KVDIM  = 256;   // H_KV * D_HEAD
static constexpr int ROWS   = 4096;  // B * T

__device__ inline unsigned short f2bf(float f) {
    __hip_bfloat16 h = __float2bfloat16(f);   // RNE
    return *reinterpret_cast<unsigned short*>(&h);
}

// ---- fused prep: block-range partitioned -------------------------------
static constexpr int XCVT_BLOCKS = (ROWS * DMODEL) / 4 / 256;      // 4096
static constexpr int WVT_BLOCKS  = (DMODEL * KVDIM) / 256;         // 1024
static constexpr int FOLD_BLOCKS = (DMODEL * KVDIM) / 256;         // 1024

__global__ void prep_kernel(const float* __restrict__ x,
                            const float* __restrict__ Wv,
                            const float* __restrict__ Wo,
                            unsigned short* __restrict__ xb,
                            unsigned short* __restrict__ WvT,
                            unsigned short* __restrict__ WeffT) {
    const int b = blockIdx.x;
    const int t = threadIdx.x;
    if (b < XCVT_BLOCKS) {
        int i = b * 256 + t;
        float4 v = reinterpret_cast<const float4*>(x)[i];
        ushort4 o;
        o.x = f2bf(v.x); o.y = f2bf(v.y); o.z = f2bf(v.z); o.w = f2bf(v.w);
        reinterpret_cast<ushort4*>(xb)[i] = o;
    } else if (b < XCVT_BLOCKS + WVT_BLOCKS) {
        // WvT[c][d] = bf16(Wv[d][c]); coalesced write, L2-absorbed read
        int idx = (b - XCVT_BLOCKS) * 256 + t;     // 256K
        int d = idx & (DMODEL - 1);
        int c = idx >> 10;
        WvT[idx] = f2bf(Wv[(size_t)d * KVDIM + c]);
    } else {
        // WeffT[m][c] = bf16( sum_{r} Wo[(4*(c>>6)+r)*64 + (c&63)][m] )
        int idx = (b - XCVT_BLOCKS - WVT_BLOCKS) * 256 + t;  // 256K
        int c = idx & (KVDIM - 1);
        int m = idx >> 8;
        const float* base =
            Wo + (size_t)((c >> 6) * 4 * 64 + (c & 63)) * DMODEL + m;
        float s = base[0]
                + base[(size_t) 64 * DMODEL]
                + base[(size_t)128 * DMODEL]
                + base[(size_t)192 * DMODEL];
        WeffT[(size_t)m * KVDIM + c] = f2bf(s);
    }
}

// ---- bf16 MFMA GEMM: C[M][N] = A[M][K] @ Bt[N][K]^T ---------------------
// 4 waves in a 2x2 grid; wave tile (AM*16)x(AN*16); block tile
// BM = 2*AM*16, BN = 2*AN*16 (= 64 here).  Triple-buffered LDS, depth-2
// prefetch, counted vmcnt, ONE s_barrier per K-step.
// Requires M%BM==0, N%BN==0, K%128==0 or nt>=2, nwg%8==0.
template<int AM, int AN, bool OUT_BF16>
__launch_bounds__(256, 2)
__global__ void gemm_bf16_mfma(const unsigned short* __restrict__ A,
                               const unsigned short* __restrict__ Bt,
                               void* __restrict__ Cout,
                               int M, int N, int K) {
    constexpr int BM  = 2 * AM * 16;
    constexpr int BN  = 2 * AN * 16;
    constexpr int ACH = BM / 32;          // A staging chunks per wave
    constexpr int BCH = BN / 32;          // B staging chunks per wave
    constexpr int LP  = ACH + BCH;        // gload_lds per wave per stage

    __shared__ short As[3][BM * 64];
    __shared__ short Bs[3][BN * 64];

    // T1: XCD-chunked bijective swizzle (nwg % 8 == 0 by construction)
    const int gx  = gridDim.x;
    const int nwg = gx * gridDim.y;
    const int bid = blockIdx.y * gx + blockIdx.x;
    const int cpx = nwg >> 3;
    const int swz = (bid & 7) * cpx + (bid >> 3);
    const int brow = (swz / gx) * BM;
    const int bcol = (swz % gx) * BN;

    const int tid  = threadIdx.x;
    const int lane = tid & 63;
    const int w    = tid >> 6;       // wave 0..3
    const int wr   = w >> 1;         // wave row (0..1)
    const int wc   = w & 1;          // wave col (0..1)

    const int lrow8 = lane >> 3;        // row within an 8-row staging chunk
    const int lkoff = (lane & 7) * 8;   // k-element offset (16B per lane)
    const int lr    = lane & 15;        // fragment row/col
    const int kg    = (lane >> 4) * 8;  // fragment k-group base

    f32x4 acc[AM][AN] = {};

    auto stage = [&](int buf, int kt) {
        #pragma unroll
        for (int i = 0; i < ACH; ++i) {
            const int ch = w * ACH + i;
            const unsigned short* g =
                A + (size_t)(brow + ch * 8 + lrow8) * K + kt + lkoff;
            __builtin_amdgcn_global_load_lds(
                (const __attribute__((address_space(1))) void*)g,
                (__attribute__((address_space(3))) void*)(&As[buf][ch * 512]),
                16, 0, 0);
        }
        #pragma unroll
        for (int i = 0; i < BCH; ++i) {
            const int ch = w * BCH + i;
            const unsigned short* g =
                Bt + (size_t)(bcol + ch * 8 + lrow8) * K + kt + lkoff;
            __builtin_amdgcn_global_load_lds(
                (const __attribute__((address_space(1))) void*)g,
                (__attribute__((address_space(3))) void*)(&Bs[buf][ch * 512]),
                16, 0, 0);
        }
    };

    const int nt = K >> 6;              // >= 2 for all our shapes
    stage(0, 0);
    stage(1, 64);
    int bc = 0;                         // buffer holding tile t
    for (int t = 0; t < nt; ++t) {
        // tile t's LP loads landed; keep tile t+1's LP in flight (never 0)
        if (t + 1 < nt) {
            if constexpr (LP == 6)
                asm volatile("s_waitcnt vmcnt(6)" ::: "memory");
            else
                asm volatile("s_waitcnt vmcnt(4)" ::: "memory");
        } else {
            asm volatile("s_waitcnt vmcnt(0)" ::: "memory");
        }
        __builtin_amdgcn_s_barrier();   // also guards WAR on buffer bs below

        int bs = bc + 2; if (bs >= 3) bs -= 3;   // == (t+2) % 3
        if (t + 2 < nt) stage(bs, (t + 2) << 6); // depth-2 prefetch in flight

        #pragma unroll
        for (int ks = 0; ks < 2; ++ks) {
            bf16x8 a[AM], b[AN];
            #pragma unroll
            for (int m = 0; m < AM; ++m)
                a[m] = *reinterpret_cast<const bf16x8*>(
                    &As[bc][(wr * AM * 16 + m * 16 + lr) * 64 + ks * 32 + kg]);
            #pragma unroll
            for (int n = 0; n < AN; ++n)
                b[n] = *reinterpret_cast<const bf16x8*>(
                    &Bs[bc][(wc * AN * 16 + n * 16 + lr) * 64 + ks * 32 + kg]);
            #pragma unroll
            for (int m = 0; m < AM; ++m)
                #pragma unroll
                for (int n = 0; n < AN; ++n)
                    acc[m][n] = __builtin_amdgcn_mfma_f32_16x16x32_bf16(
                        a[m], b[n], acc[m][n], 0, 0, 0);
        }
        bc = (bc == 2) ? 0 : bc + 1;
    }

    // C/D layout: col = lane&15, row = (lane>>4)*4 + reg  (guide m89/m91)
    const int rg = (lane >> 4) * 4;
    #pragma unroll
    for (int m = 0; m < AM; ++m) {
        #pragma unroll
        for (int n = 0; n < AN; ++n) {
            #pragma unroll
            for (int j = 0; j < 4; ++j) {
                const size_t row = brow + wr * AM * 16 + m * 16 + rg + j;
                const size_t col = bcol + wc * AN * 16 + n * 16 + lr;
                if (OUT_BF16)
                    ((unsigned short*)Cout)[row * N + col] = f2bf(acc[m][n][j]);
                else
                    ((float*)Cout)[row * N + col] = acc[m][n][j];
            }
        }
    }
}

extern "C" void kernel_launch(void* const* d_in, const int* in_sizes, int n_in,
                              void* d_out, int out_size, void* d_ws, size_t ws_size,
                              hipStream_t stream) {
    const float* x  = (const float*)d_in[0];   // (4096, 1024)
    const float* Wv = (const float*)d_in[3];   // (1024, 256)
    const float* Wo = (const float*)d_in[4];   // (1024, 1024)
    float* out = (float*)d_out;                // (4096, 1024) f32

    unsigned short* xb    = (unsigned short*)d_ws;           // 8 MB
    unsigned short* WvT   = xb    + (size_t)ROWS * DMODEL;   // 0.5 MB [c][d]
    unsigned short* WeffT = WvT   + (size_t)KVDIM * DMODEL;  // 0.5 MB [m][c]
    unsigned short* Vb    = WeffT + (size_t)DMODEL * KVDIM;  // 2 MB   [r][c]

    prep_kernel<<<XCVT_BLOCKS + WVT_BLOCKS + FOLD_BLOCKS, 256, 0, stream>>>(
        x, Wv, Wo, xb, WvT, WeffT);

    // Vb[r][c] = sum_d xb[r][d] * WvT[c][d]    (M=4096, N=256, K=1024)
    gemm_bf16_mfma<2, 2, true><<<dim3(KVDIM / 64, ROWS / 64), 256, 0, stream>>>(
        xb, WvT, Vb, ROWS, KVDIM, DMODEL);

    // out[r][m] = sum_c Vb[r][c] * WeffT[m][c] (M=4096, N=1024, K=256)
    gemm_bf16_mfma<4, 2, false><<<dim3(DMODEL / 64, ROWS / 128), 256, 0, stream>>>(
        Vb, WeffT, out, ROWS, DMODEL, KVDIM);
}